// Round 12
// baseline (148.863 us; speedup 1.0000x reference)
//
#include <hip/hip_runtime.h>
#include <hip/hip_bf16.h>
#include <hip/hip_fp16.h>
#include <math.h>

#define B_  16
#define N_  256
#define D_  1024
#define H_  8
#define DK_ 128

typedef unsigned short u16;
typedef __attribute__((ext_vector_type(8))) short s8v;   // 8 bf16 MFMA A/B frag
typedef __attribute__((ext_vector_type(4))) float f4v;   // MFMA C/D frag

__device__ __forceinline__ u16 f2b(float x) {
    union { float f; unsigned u; } v; v.f = x;
    unsigned r = v.u + 0x7fffu + ((v.u >> 16) & 1u);   // RNE
    return (u16)(r >> 16);
}

__device__ __forceinline__ void gload16(void* lds, const void* g) {
    __builtin_amdgcn_global_load_lds(
        (const __attribute__((address_space(1))) void*)g,
        (__attribute__((address_space(3))) void*)lds, 16, 0, 0);
}

__device__ __forceinline__ void waitv16() { asm volatile("s_waitcnt vmcnt(16)" ::: "memory"); }
__device__ __forceinline__ void waitv8()  { asm volatile("s_waitcnt vmcnt(8)"  ::: "memory"); }
__device__ __forceinline__ void waitv0()  { asm volatile("s_waitcnt vmcnt(0)"  ::: "memory"); }
__device__ __forceinline__ void waitlgkm0() {
    asm volatile("s_waitcnt lgkmcnt(0)" ::: "memory");
    __builtin_amdgcn_sched_barrier(0);   // rule 18: pin drain vs re-stage
}

// ---------------------------------------------------------------------------
// fp32 -> bf16 convert, 8 elems/thread; blockIdx.y selects q/k/v input.
// ---------------------------------------------------------------------------
__global__ __launch_bounds__(256)
void cvt_kernel(const float* __restrict__ x0, const float* __restrict__ x1,
                const float* __restrict__ x2, u16* __restrict__ out)
{
    const float* in = (blockIdx.y == 0) ? x0 : (blockIdx.y == 1) ? x1 : x2;
    u16* o = out + (size_t)blockIdx.y * 4194304;
    const int i = blockIdx.x * 256 + threadIdx.x;
    const float4 a = ((const float4*)in)[2 * i];
    const float4 b = ((const float4*)in)[2 * i + 1];
    union { u16 s[8]; uint4 v; } t;
    t.s[0] = f2b(a.x); t.s[1] = f2b(a.y); t.s[2] = f2b(a.z); t.s[3] = f2b(a.w);
    t.s[4] = f2b(b.x); t.s[5] = f2b(b.y); t.s[6] = f2b(b.z); t.s[7] = f2b(b.w);
    ((uint4*)o)[i] = t.v;
}

// ---------------------------------------------------------------------------
// Weight convert + transpose: W[K][N] fp32 -> Wt[N][K] bf16 (z selects).
// ---------------------------------------------------------------------------
__global__ __launch_bounds__(256)
void cvtT_kernel(const float* __restrict__ W0, const float* __restrict__ W1,
                 const float* __restrict__ W2, const float* __restrict__ W3,
                 u16* __restrict__ out)
{
    const float* W = (blockIdx.z == 0) ? W0 : (blockIdx.z == 1) ? W1 :
                     (blockIdx.z == 2) ? W2 : W3;
    u16* o = out + (size_t)blockIdx.z * (D_ * D_);
    __shared__ float t[32][33];
    const int k0 = blockIdx.x * 32, n0 = blockIdx.y * 32;
    const int c = threadIdx.x & 31, r8 = threadIdx.x >> 5;
#pragma unroll
    for (int rr = 0; rr < 4; ++rr)
        t[r8 + rr * 8][c] = W[(size_t)(k0 + r8 + rr * 8) * D_ + n0 + c];
    __syncthreads();
#pragma unroll
    for (int rr = 0; rr < 4; ++rr)
        o[(size_t)(n0 + r8 + rr * 8) * D_ + k0 + c] = f2b(t[c][r8 + rr * 8]);
}

// ---------------------------------------------------------------------------
// WAVE-AUTONOMOUS bf16 MFMA GEMM — zero barriers.
// One 64-thread block = one wave owning a 64x64 output tile with private
// triple-buffered LDS (3 x (4+4) KB).  The wave stages its own K-tiles via
// global_load_lds; producer == consumer, so correctness needs only:
//   - counted vmcnt (prologue 16 out; steady waitv16 => tile kt landed;
//     tail waitv8 / waitv0),
//   - lgkmcnt(0)+sched_barrier before re-staging a buffer (ds_read drain).
// Per K-step: 8 gload + 8 ds_read_b128 (~64cy) + 16 MFMA (~77cy) - balanced.
// 6 waves/CU (LDS-capped) run unsynchronized -> latency hidden by TLP.
// Swizzle: same (srccol ^ (row>>1)&3) involution as r6 (conflict-free).
// XCD swizzle: 8 m-panels/XCD, n outer (A 1MB + B 2MB L2-resident/XCD).
// MODE 0: fp32 out row-major. MODE 1: bf16 qkv scatter (z=2 transposed).
// ---------------------------------------------------------------------------
template<int MODE>
__global__ __launch_bounds__(64)
void wgemm_kernel(const u16* __restrict__ A0, const u16* __restrict__ Wt0,
                  const float* __restrict__ b0, const float* __restrict__ b1,
                  const float* __restrict__ b2, void* __restrict__ outb)
{
    __shared__ __align__(16) u16 As[3][64][32];   // 12 KB
    __shared__ __align__(16) u16 Bs[3][64][32];   // 12 KB

    const int z = blockIdx.z;
    const u16* A  = A0  + (size_t)z * 4194304;
    const u16* Wt = Wt0 + (size_t)z * 1048576;
    const float* bias = (z == 0) ? b0 : (z == 1) ? b1 : b2;

    // XCD swizzle: 1024 blocks/slice; xcd owns 8 m-panels, m inner, n outer
    const int bid = blockIdx.x;
    const int xcd = bid & 7;
    const int wic = bid >> 3;                  // 0..127
    const int by  = xcd * 8 + (wic & 7);       // m-tile 0..63
    const int bx  = wic >> 3;                  // n-tile 0..15
    const int m0  = by * 64;
    const int n0  = bx * 64;

    const int lane = threadIdx.x;              // 0..63
    const int l15  = lane & 15;
    const int l4   = lane >> 4;

    // staging map: instr i stages rows [i*16, i*16+16); lane -> row i*16+(lane>>2),
    // 16B chunk (lane&3).  LDS dest byte = i*1024 + lane*16 (linear).  Global
    // source col XOR-swizzled (involution with frag-read col).
    const int srow = lane >> 2;                // 0..15
    const int sch  = lane & 3;
    const int scol = (sch ^ ((srow >> 1) & 3)) * 8;
    const u16* aS = A  + (size_t)(m0 + srow) * 1024 + scol;
    const u16* bS = Wt + (size_t)(n0 + srow) * 1024 + scol;
    const int fc = (l4 ^ ((l15 >> 1) & 3)) * 8;   // frag-read swizzled col

    auto stage = [&](int buf, int kt) {
        const int k0_ = kt * 32;
#pragma unroll
        for (int i = 0; i < 4; ++i)
            gload16(&As[buf][i * 16 + srow][sch * 8], aS + (size_t)i * 16 * 1024 + k0_);
#pragma unroll
        for (int i = 0; i < 4; ++i)
            gload16(&Bs[buf][i * 16 + srow][sch * 8], bS + (size_t)i * 16 * 1024 + k0_);
    };

    f4v acc[4][4] = {};

    stage(0, 0);
    stage(1, 1);           // 16 loads outstanding

    for (int kt = 0; kt < 32; ++kt) {
        const int cur = kt % 3;
        waitlgkm0();                       // prev tile's ds_reads drained
        if (kt < 30) stage((kt + 2) % 3, kt + 2);
        if (kt < 30)      waitv16();       // tile kt's 8 loads landed
        else if (kt == 30) waitv8();
        else               waitv0();

        s8v af[4], bf[4];
#pragma unroll
        for (int i = 0; i < 4; ++i)
            af[i] = *(const s8v*)&As[cur][i * 16 + l15][fc];
#pragma unroll
        for (int j = 0; j < 4; ++j)
            bf[j] = *(const s8v*)&Bs[cur][j * 16 + l15][fc];
#pragma unroll
        for (int i = 0; i < 4; ++i)
#pragma unroll
            for (int j = 0; j < 4; ++j)
                acc[i][j] = __builtin_amdgcn_mfma_f32_16x16x32_bf16(
                    af[i], bf[j], acc[i][j], 0, 0, 0);
    }

    // epilogue: C/D layout col = lane&15 (n), row = (lane>>4)*4 + reg (m)
#pragma unroll
    for (int j = 0; j < 4; ++j) {
        const int n = n0 + j * 16 + l15;
        const float bb = bias[n];
#pragma unroll
        for (int i = 0; i < 4; ++i) {
            const int mbase = m0 + i * 16 + l4 * 4;
            if constexpr (MODE == 0) {
#pragma unroll
                for (int reg = 0; reg < 4; ++reg)
                    ((float*)outb)[(size_t)(mbase + reg) * 1024 + n] =
                        acc[i][j][reg] + bb;
            } else {
                if (z == 2) {
                    // transposed V: [B,H,DK,N], 4 consecutive tok -> ushort4
                    const int b = mbase >> 8, tok = mbase & 255;
                    const int h = n >> 7, d = n & 127;
                    ushort4 st;
                    st.x = f2b(acc[i][j][0] + bb);
                    st.y = f2b(acc[i][j][1] + bb);
                    st.z = f2b(acc[i][j][2] + bb);
                    st.w = f2b(acc[i][j][3] + bb);
                    *(ushort4*)&((u16*)outb)[(size_t)z * 4194304 +
                        (((size_t)b * H_ + h) * DK_ + d) * N_ + tok] = st;
                } else {
                    const int h = n >> 7, d = n & 127;
#pragma unroll
                    for (int reg = 0; reg < 4; ++reg) {
                        const int m = mbase + reg;
                        const int b = m >> 8, tok = m & 255;
                        ((u16*)outb)[(size_t)z * 4194304 +
                            (((size_t)b * H_ + h) * N_ + tok) * DK_ + d] =
                            f2b(acc[i][j][reg] + bb);
                    }
                }
            }
        }
    }
}

// ---------------------------------------------------------------------------
// Fused box relational embedding -> per-head Linear(64->1) -> relu -> log.
// Output fp16 [B,H,N,N].  Inner dot vectorized (float4 LDS reads).
// ---------------------------------------------------------------------------
__global__ __launch_bounds__(256)
void boxbias_kernel(const float* __restrict__ fg, const float* __restrict__ Wg,
                    const float* __restrict__ bg, _Float16* __restrict__ lb)
{
    __shared__ __align__(16) float sWg[512];
    __shared__ float sbg[8];
    const int tid = threadIdx.x;
    const int b = blockIdx.x >> 8;
    const int i = blockIdx.x & 255;

    sWg[tid] = Wg[tid];
    sWg[tid + 256] = Wg[tid + 256];
    if (tid < 8) sbg[tid] = bg[tid];

    const float4 bi = *(const float4*)&fg[(size_t)(b * N_ + i) * 4];
    const float cxi = 0.5f * (bi.x + bi.z);
    const float cyi = 0.5f * (bi.y + bi.w);
    const float wi  = bi.z - bi.x + 1.0f;
    const float hi  = bi.w - bi.y + 1.0f;

    const int j = tid;
    const float4 bj = *(const float4*)&fg[(size_t)(b * N_ + j) * 4];
    const float cxj = 0.5f * (bj.x + bj.z);
    const float cyj = 0.5f * (bj.y + bj.w);
    const float wj  = bj.z - bj.x + 1.0f;
    const float hj  = bj.w - bj.y + 1.0f;

    const float pos[4] = {
        logf(fmaxf(fabsf((cxi - cxj) / wi), 1e-3f)) * 100.0f,
        logf(fmaxf(fabsf((cyi - cyj) / hi), 1e-3f)) * 100.0f,
        logf(wi / wj) * 100.0f,
        logf(hi / hj) * 100.0f
    };
    const float dim[8] = {1.0f, 0.421696503f, 0.177827941f, 0.0749894209f,
                          0.0316227766f, 0.0133352143f, 0.00562341325f, 0.00237137371f};

    float sv[32], cv[32];
#pragma unroll
    for (int p = 0; p < 4; ++p)
#pragma unroll
        for (int q = 0; q < 8; ++q)
            __sincosf(pos[p] * dim[q], &sv[p * 8 + q], &cv[p * 8 + q]);

    __syncthreads();
#pragma unroll
    for (int h = 0; h < 8; ++h) {
        float acc = sbg[h];
        const float* wrow = &sWg[h * 64];
#pragma unroll
        for (int g0 = 0; g0 < 32; g0 += 4) {
            const float4 ws = *(const float4*)&wrow[g0];
            const float4 wc = *(const float4*)&wrow[32 + g0];
            acc = fmaf(sv[g0 + 0], ws.x, fmaf(cv[g0 + 0], wc.x, acc));
            acc = fmaf(sv[g0 + 1], ws.y, fmaf(cv[g0 + 1], wc.y, acc));
            acc = fmaf(sv[g0 + 2], ws.z, fmaf(cv[g0 + 2], wc.z, acc));
            acc = fmaf(sv[g0 + 3], ws.w, fmaf(cv[g0 + 3], wc.w, acc));
        }
        const float rel = fmaxf(acc, 0.0f);
        lb[(((size_t)b * H_ + h) * N_ + i) * N_ + j] =
            (_Float16)logf(fmaxf(rel, 1e-6f));
    }
}

// ---------------------------------------------------------------------------
// MFMA flash attention.  Block = (b*H+h, q-quarter): 64 queries, 4 waves x
// 16 q each.  512 blocks -> 2 blocks/CU co-residency.
// vp is TRANSPOSED [B,H,DK,N] -> Vt staged with vector loads/writes.
// ---------------------------------------------------------------------------
__global__ __launch_bounds__(256)
void attn_mfma_kernel(const u16* __restrict__ qp, const u16* __restrict__ kp,
                      const u16* __restrict__ vp, const _Float16* __restrict__ lb,
                      u16* __restrict__ ao)
{
    __shared__ __align__(16) u16 Ks[32][136];
    __shared__ __align__(16) u16 Vt[128][40];
    __shared__ __align__(16) u16 Ps[4][16][40];

    const int tid  = threadIdx.x;
    const int lane = tid & 63;
    const int w    = tid >> 6;
    const int l15  = lane & 15;
    const int l4   = lane >> 4;
    const int bh   = blockIdx.x >> 2;
    const int qt   = blockIdx.x & 3;
    const int q0   = qt * 64 + w * 16;

    s8v qf[4];
    const u16* qb = qp + ((size_t)bh * N_ + q0) * DK_;
#pragma unroll
    for (int ks = 0; ks < 4; ++ks)
        qf[ks] = *(const s8v*)(qb + (size_t)l15 * DK_ + ks * 32 + l4 * 8);

    f4v o[8] = {};
    float m_r[4], l_r[4];
#pragma unroll
    for (int r = 0; r < 4; ++r) { m_r[r] = -INFINITY; l_r[r] = 0.0f; }

    const float scale = 0.08838834764831845f;
    const _Float16* lbb = lb + ((size_t)bh * N_ + q0) * N_;

    const int sr = tid >> 3;
    const int sc = (tid & 7) * 16;
    const int vr = tid >> 2;
    const int vs = (tid & 3) * 8;

    for (int kt = 0; kt < 8; ++kt) {
        __syncthreads();
        {
            const u16* ksrc = kp + ((size_t)bh * N_ + kt * 32) * DK_;
            *(s8v*)&Ks[sr][sc]     = *(const s8v*)(ksrc + (size_t)sr * DK_ + sc);
            *(s8v*)&Ks[sr][sc + 8] = *(const s8v*)(ksrc + (size_t)sr * DK_ + sc + 8);
        }
        {
            const u16* vsrc = vp + ((size_t)bh * DK_ + vr) * N_ + kt * 32 + vs;
            const s8v v0 = *(const s8v*)vsrc;
            const s8v v1 = *(const s8v*)(vsrc + 64 * N_);
            *(s8v*)&Vt[vr][vs]      = v0;
            *(s8v*)&Vt[vr + 64][vs] = v1;
        }
        __syncthreads();

        f4v s[2] = {};
#pragma unroll
        for (int ks = 0; ks < 4; ++ks) {
#pragma unroll
            for (int kf = 0; kf < 2; ++kf) {
                const s8v kb = *(const s8v*)&Ks[kf * 16 + l15][ks * 32 + l4 * 8];
                s[kf] = __builtin_amdgcn_mfma_f32_16x16x32_bf16(
                    qf[ks], kb, s[kf], 0, 0, 0);
            }
        }
#pragma unroll
        for (int kf = 0; kf < 2; ++kf)
#pragma unroll
            for (int r = 0; r < 4; ++r)
                s[kf][r] = fmaf(s[kf][r], scale, (float)
                    lbb[(size_t)(l4 * 4 + r) * N_ + kt * 32 + kf * 16 + l15]);

        {
            float rm[4], al[4];
#pragma unroll
            for (int r = 0; r < 4; ++r) rm[r] = fmaxf(s[0][r], s[1][r]);
#pragma unroll
            for (int st = 1; st <= 8; st <<= 1)
#pragma unroll
                for (int r = 0; r < 4; ++r) rm[r] = fmaxf(rm[r], __shfl_xor(rm[r], st));
#pragma unroll
            for (int r = 0; r < 4; ++r) {
                const float mn = fmaxf(m_r[r], rm[r]);
                al[r] = __expf(m_r[r] - mn);
                m_r[r] = mn;
            }
            float p0[4], p1[4], rs[4];
#pragma unroll
            for (int r = 0; r < 4; ++r) {
                p0[r] = __expf(s[0][r] - m_r[r]);
                p1[r] = __expf(s[1][r] - m_r[r]);
                rs[r] = p0[r] + p1[r];
            }
#pragma unroll
            for (int st = 1; st <= 8; st <<= 1)
#pragma unroll
                for (int r = 0; r < 4; ++r) rs[r] += __shfl_xor(rs[r], st);
#pragma unroll
            for (int r = 0; r < 4; ++r) {
                l_r[r] = l_r[r] * al[r] + rs[r];
                Ps[w][l4 * 4 + r][l15]      = f2b(p0[r]);
                Ps[w][l4 * 4 + r][16 + l15] = f2b(p1[r]);
            }
#pragma unroll
            for (int nf = 0; nf < 8; ++nf)
#pragma unroll
                for (int r = 0; r < 4; ++r) o[nf][r] *= al[r];
        }

        const s8v pa = *(const s8v*)&Ps[w][l15][l4 * 8];
#pragma unroll
        for (int nf = 0; nf < 8; ++nf) {
            const s8v vb = *(const s8v*)&Vt[nf * 16 + l15][l4 * 8];
            o[nf] = __builtin_amdgcn_mfma_f32_16x16x32_bf16(pa, vb, o[nf], 0, 0, 0);
        }
    }

    const int b = bh >> 3, h = bh & 7;
    float inv[4];
#pragma unroll
    for (int r = 0; r < 4; ++r) inv[r] = 1.0f / l_r[r];
#pragma unroll
    for (int nf = 0; nf < 8; ++nf) {
#pragma unroll
        for (int r = 0; r < 4; ++r) {
            const int tok = q0 + l4 * 4 + r;
            const int d = nf * 16 + l15;
            ao[(((size_t)b * N_ + tok) * H_ + h) * DK_ + d] = f2b(o[nf][r] * inv[r]);
        }
    }
}

// ---------------------------------------------------------------------------
// Workspace (88 MiB used):
//   xb 24 MiB | Wt 8 MiB | qkv 24 MiB | lb(fp16) 16 MiB | ao 8 MiB
// ---------------------------------------------------------------------------
extern "C" void kernel_launch(void* const* d_in, const int* in_sizes, int n_in,
                              void* d_out, int out_size, void* d_ws, size_t ws_size,
                              hipStream_t stream)
{
    const float* xq = (const float*)d_in[0];
    const float* xk = (const float*)d_in[1];
    const float* xv = (const float*)d_in[2];
    const float* fg = (const float*)d_in[3];
    const float* Wq = (const float*)d_in[4];
    const float* bq = (const float*)d_in[5];
    const float* Wk = (const float*)d_in[6];
    const float* bk = (const float*)d_in[7];
    const float* Wv = (const float*)d_in[8];
    const float* bv = (const float*)d_in[9];
    const float* Wg = (const float*)d_in[10];
    const float* bg = (const float*)d_in[11];
    const float* Wo = (const float*)d_in[12];
    const float* bo = (const float*)d_in[13];

    char* w8 = (char*)d_ws;
    u16*      xb  = (u16*)(w8);
    u16*      Wt  = (u16*)(w8 + 25165824);
    u16*      qkv = (u16*)(w8 + 33554432);
    _Float16* lb  = (_Float16*)(w8 + 58720256);
    u16*      ao  = (u16*)(w8 + 75497472);

    cvt_kernel<<<dim3(2048, 3), 256, 0, stream>>>(xq, xk, xv, xb);
    cvtT_kernel<<<dim3(32, 32, 4), 256, 0, stream>>>(Wq, Wk, Wv, Wo, Wt);

    // qkv projection: wave-autonomous, 1024 blocks/slice x 3, 64 thr
    wgemm_kernel<1><<<dim3(1024, 1, 3), 64, 0, stream>>>(
        xb, Wt, bq, bk, bv, qkv);

    boxbias_kernel<<<B_ * N_, 256, 0, stream>>>(fg, Wg, bg, lb);

    attn_mfma_kernel<<<512, 256, 0, stream>>>(
        qkv, qkv + 4194304, qkv + 2 * 4194304, lb, ao);

    // output projection: wave-autonomous, 1024 blocks, 64 thr
    wgemm_kernel<0><<<dim3(1024, 1, 1), 64, 0, stream>>>(
        ao, Wt + 3 * 1048576, bo, bo, bo, d_out);
}

// Round 13
// 129.023 us; speedup vs baseline: 1.1538x; 1.1538x over previous
//
#include <hip/hip_runtime.h>
#include <hip/hip_bf16.h>
#include <hip/hip_fp16.h>
#include <math.h>

#define B_  16
#define N_  256
#define D_  1024
#define H_  8
#define DK_ 128

typedef unsigned short u16;
typedef __attribute__((ext_vector_type(8))) short s8v;   // 8 bf16 MFMA A/B frag
typedef __attribute__((ext_vector_type(4))) float f4v;   // MFMA C/D frag

__device__ __forceinline__ u16 f2b(float x) {
    union { float f; unsigned u; } v; v.f = x;
    unsigned r = v.u + 0x7fffu + ((v.u >> 16) & 1u);   // RNE
    return (u16)(r >> 16);
}

__device__ __forceinline__ void gload16(void* lds, const void* g) {
    __builtin_amdgcn_global_load_lds(
        (const __attribute__((address_space(1))) void*)g,
        (__attribute__((address_space(3))) void*)lds, 16, 0, 0);
}

// counted vmcnt waits (literal asm, memory clobber pins surrounding mem ops)
__device__ __forceinline__ void waitv8() { asm volatile("s_waitcnt vmcnt(8)" ::: "memory"); }
__device__ __forceinline__ void waitv6() { asm volatile("s_waitcnt vmcnt(6)" ::: "memory"); }
__device__ __forceinline__ void waitv4() { asm volatile("s_waitcnt vmcnt(4)" ::: "memory"); }
__device__ __forceinline__ void waitv3() { asm volatile("s_waitcnt vmcnt(3)" ::: "memory"); }
__device__ __forceinline__ void waitv0() { asm volatile("s_waitcnt vmcnt(0)" ::: "memory"); }
__device__ __forceinline__ void membar() { asm volatile("" ::: "memory"); }

// ---------------------------------------------------------------------------
// fp32 -> bf16 convert, 8 elems/thread; blockIdx.y selects q/k/v input.
// ---------------------------------------------------------------------------
__global__ __launch_bounds__(256)
void cvt_kernel(const float* __restrict__ x0, const float* __restrict__ x1,
                const float* __restrict__ x2, u16* __restrict__ out)
{
    const float* in = (blockIdx.y == 0) ? x0 : (blockIdx.y == 1) ? x1 : x2;
    u16* o = out + (size_t)blockIdx.y * 4194304;
    const int i = blockIdx.x * 256 + threadIdx.x;
    const float4 a = ((const float4*)in)[2 * i];
    const float4 b = ((const float4*)in)[2 * i + 1];
    union { u16 s[8]; uint4 v; } t;
    t.s[0] = f2b(a.x); t.s[1] = f2b(a.y); t.s[2] = f2b(a.z); t.s[3] = f2b(a.w);
    t.s[4] = f2b(b.x); t.s[5] = f2b(b.y); t.s[6] = f2b(b.z); t.s[7] = f2b(b.w);
    ((uint4*)o)[i] = t.v;
}

// ---------------------------------------------------------------------------
// Weight convert + transpose: W[K][N] fp32 -> Wt[N][K] bf16 (z selects).
// ---------------------------------------------------------------------------
__global__ __launch_bounds__(256)
void cvtT_kernel(const float* __restrict__ W0, const float* __restrict__ W1,
                 const float* __restrict__ W2, const float* __restrict__ W3,
                 u16* __restrict__ out)
{
    const float* W = (blockIdx.z == 0) ? W0 : (blockIdx.z == 1) ? W1 :
                     (blockIdx.z == 2) ? W2 : W3;
    u16* o = out + (size_t)blockIdx.z * (D_ * D_);
    __shared__ float t[32][33];
    const int k0 = blockIdx.x * 32, n0 = blockIdx.y * 32;
    const int c = threadIdx.x & 31, r8 = threadIdx.x >> 5;
#pragma unroll
    for (int rr = 0; rr < 4; ++rr)
        t[r8 + rr * 8][c] = W[(size_t)(k0 + r8 + rr * 8) * D_ + n0 + c];
    __syncthreads();
#pragma unroll
    for (int rr = 0; rr < 4; ++rr)
        o[(size_t)(n0 + r8 + rr * 8) * D_ + k0 + c] = f2b(t[c][r8 + rr * 8]);
}

// ---------------------------------------------------------------------------
// bf16 MFMA GEMM, 3-deep buffered K-pipeline with counted vmcnt (T4).
// out = A[4096,1024] @ Wt[1024,1024]^T + bias.  BN=128, BK=32, 256 thr =
// 4 waves (2 x 2), wave tile WM x 64, FM x 4 16x16 frags.
//   BM=128/FM=4/LOADS=4 : qkv projection (MODE 1, z batches slices)
//   BM=128/FM=4/LOADS=4/MODE=0 : output proj (256 blocks, 1/CU) — 16 MFMA
//     per K-step amortizes the fixed stage+wait+barrier cost (r12 A/B).
// Schedule per K-step: bar; STAGE(kt+2); vmcnt(2L) [tile kt landed]; bar;
// ds_read + MFMA.  Loads stay in flight across 2 compute phases (~HBM lat).
// Bank-conflict-free via XOR swizzle on (source col, read col) pair.
// ---------------------------------------------------------------------------
template<int BM, int FM, int LOADS, int MODE>
__global__ __launch_bounds__(256)
void gemm_kernel(const u16* __restrict__ A0, const u16* __restrict__ Wt0,
                 const float* __restrict__ b0, const float* __restrict__ b1,
                 const float* __restrict__ b2, void* __restrict__ outb)
{
    constexpr int WM  = FM * 16;
    constexpr int MT8 = (4096 / BM) / 8;   // m-tiles per XCD chunk
    __shared__ __align__(16) u16 As[3][BM][32];
    __shared__ __align__(16) u16 Bs[3][128][32];

    const int z = blockIdx.z;
    const u16* A  = A0  + (size_t)z * 4194304;
    const u16* Wt = Wt0 + (size_t)z * 1048576;
    const float* bias = (z == 0) ? b0 : (z == 1) ? b1 : b2;

    // bijective XCD-chunk swizzle
    const int bid = blockIdx.x;
    const int xcd = bid & 7;
    const int wic = bid >> 3;
    const int by  = xcd * MT8 + (wic & (MT8 - 1));
    const int bx  = wic / MT8;
    const int m0  = by * BM;
    const int n0  = bx * 128;

    const int tid  = threadIdx.x;
    const int lane = tid & 63;
    const int w    = tid >> 6;
    const int l15  = lane & 15;
    const int l4   = lane >> 4;
    const int wr   = w >> 1;
    const int wc   = w & 1;

    // staging: thread t -> row t>>2, 16B chunk c4; LDS dest linear,
    // global source col XOR-swizzled (involution with frag-read col)
    const int gr   = tid >> 2;
    const int c4   = tid & 3;
    const int scol = (c4 ^ ((gr >> 1) & 3)) * 8;
    const int doff = c4 * 8;
    const u16* asrc = A  + (size_t)(m0 + gr) * 1024 + scol;
    const u16* bsrc = Wt + (size_t)(n0 + gr) * 1024 + scol;
    const int fc = (l4 ^ ((l15 >> 1) & 3)) * 8;   // frag-read swizzled col

    auto stage = [&](int buf, int kt) {
        const int k0_ = kt * 32;
        gload16(&As[buf][gr][doff], asrc + k0_);
        if constexpr (BM == 128)
            gload16(&As[buf][gr + 64][doff], asrc + 64 * 1024 + k0_);
        gload16(&Bs[buf][gr][doff], bsrc + k0_);
        gload16(&Bs[buf][gr + 64][doff], bsrc + 64 * 1024 + k0_);
    };

    f4v acc[FM][4] = {};

    stage(0, 0);
    stage(1, 1);
    int cur = 0, stg = 2;

    for (int kt = 0; kt < 32; ++kt) {
        membar();
        __builtin_amdgcn_s_barrier();   // prior reads of buf[stg] done
        if (kt < 30) {
            stage(stg, kt + 2);
            if constexpr (LOADS == 4) waitv8(); else waitv6();
        } else if (kt == 30) {
            if constexpr (LOADS == 4) waitv4(); else waitv3();
        } else {
            waitv0();
        }
        membar();
        __builtin_amdgcn_s_barrier();   // tile kt fully in LDS for all waves

        s8v af[FM], bf[4];
#pragma unroll
        for (int i = 0; i < FM; ++i)
            af[i] = *(const s8v*)&As[cur][wr * WM + i * 16 + l15][fc];
#pragma unroll
        for (int j = 0; j < 4; ++j)
            bf[j] = *(const s8v*)&Bs[cur][wc * 64 + j * 16 + l15][fc];
#pragma unroll
        for (int i = 0; i < FM; ++i)
#pragma unroll
            for (int j = 0; j < 4; ++j)
                acc[i][j] = __builtin_amdgcn_mfma_f32_16x16x32_bf16(
                    af[i], bf[j], acc[i][j], 0, 0, 0);

        cur = (cur == 2) ? 0 : cur + 1;
        stg = (stg == 2) ? 0 : stg + 1;
    }

    // epilogue: C/D layout col = lane&15, row = (lane>>4)*4 + reg
#pragma unroll
    for (int j = 0; j < 4; ++j) {
        const int n = n0 + wc * 64 + j * 16 + l15;
        const float bb = bias[n];
#pragma unroll
        for (int i = 0; i < FM; ++i) {
            const int mbase = m0 + wr * WM + i * 16 + l4 * 4;
            if constexpr (MODE == 0) {
#pragma unroll
                for (int reg = 0; reg < 4; ++reg)
                    ((float*)outb)[(size_t)(mbase + reg) * 1024 + n] =
                        acc[i][j][reg] + bb;
            } else {
                if (z == 2) {
                    // transposed V: [B,H,DK,N], 4 consecutive tok -> ushort4
                    const int b = mbase >> 8, tok = mbase & 255;
                    const int h = n >> 7, d = n & 127;
                    ushort4 st;
                    st.x = f2b(acc[i][j][0] + bb);
                    st.y = f2b(acc[i][j][1] + bb);
                    st.z = f2b(acc[i][j][2] + bb);
                    st.w = f2b(acc[i][j][3] + bb);
                    *(ushort4*)&((u16*)outb)[(size_t)z * 4194304 +
                        (((size_t)b * H_ + h) * DK_ + d) * N_ + tok] = st;
                } else {
                    const int h = n >> 7, d = n & 127;
#pragma unroll
                    for (int reg = 0; reg < 4; ++reg) {
                        const int m = mbase + reg;
                        const int b = m >> 8, tok = m & 255;
                        ((u16*)outb)[(size_t)z * 4194304 +
                            (((size_t)b * H_ + h) * N_ + tok) * DK_ + d] =
                            f2b(acc[i][j][reg] + bb);
                    }
                }
            }
        }
    }
}

// ---------------------------------------------------------------------------
// Fused box relational embedding -> per-head Linear(64->1) -> relu -> log.
// Output fp16 [B,H,N,N].  Inner dot vectorized (float4 LDS reads).
// ---------------------------------------------------------------------------
__global__ __launch_bounds__(256)
void boxbias_kernel(const float* __restrict__ fg, const float* __restrict__ Wg,
                    const float* __restrict__ bg, _Float16* __restrict__ lb)
{
    __shared__ __align__(16) float sWg[512];
    __shared__ float sbg[8];
    const int tid = threadIdx.x;
    const int b = blockIdx.x >> 8;
    const int i = blockIdx.x & 255;

    sWg[tid] = Wg[tid];
    sWg[tid + 256] = Wg[tid + 256];
    if (tid < 8) sbg[tid] = bg[tid];

    const float4 bi = *(const float4*)&fg[(size_t)(b * N_ + i) * 4];
    const float cxi = 0.5f * (bi.x + bi.z);
    const float cyi = 0.5f * (bi.y + bi.w);
    const float wi  = bi.z - bi.x + 1.0f;
    const float hi  = bi.w - bi.y + 1.0f;

    const int j = tid;
    const float4 bj = *(const float4*)&fg[(size_t)(b * N_ + j) * 4];
    const float cxj = 0.5f * (bj.x + bj.z);
    const float cyj = 0.5f * (bj.y + bj.w);
    const float wj  = bj.z - bj.x + 1.0f;
    const float hj  = bj.w - bj.y + 1.0f;

    const float pos[4] = {
        logf(fmaxf(fabsf((cxi - cxj) / wi), 1e-3f)) * 100.0f,
        logf(fmaxf(fabsf((cyi - cyj) / hi), 1e-3f)) * 100.0f,
        logf(wi / wj) * 100.0f,
        logf(hi / hj) * 100.0f
    };
    const float dim[8] = {1.0f, 0.421696503f, 0.177827941f, 0.0749894209f,
                          0.0316227766f, 0.0133352143f, 0.00562341325f, 0.00237137371f};

    float sv[32], cv[32];
#pragma unroll
    for (int p = 0; p < 4; ++p)
#pragma unroll
        for (int q = 0; q < 8; ++q)
            __sincosf(pos[p] * dim[q], &sv[p * 8 + q], &cv[p * 8 + q]);

    __syncthreads();
#pragma unroll
    for (int h = 0; h < 8; ++h) {
        float acc = sbg[h];
        const float* wrow = &sWg[h * 64];
#pragma unroll
        for (int g0 = 0; g0 < 32; g0 += 4) {
            const float4 ws = *(const float4*)&wrow[g0];
            const float4 wc = *(const float4*)&wrow[32 + g0];
            acc = fmaf(sv[g0 + 0], ws.x, fmaf(cv[g0 + 0], wc.x, acc));
            acc = fmaf(sv[g0 + 1], ws.y, fmaf(cv[g0 + 1], wc.y, acc));
            acc = fmaf(sv[g0 + 2], ws.z, fmaf(cv[g0 + 2], wc.z, acc));
            acc = fmaf(sv[g0 + 3], ws.w, fmaf(cv[g0 + 3], wc.w, acc));
        }
        const float rel = fmaxf(acc, 0.0f);
        lb[(((size_t)b * H_ + h) * N_ + i) * N_ + j] =
            (_Float16)logf(fmaxf(rel, 1e-6f));
    }
}

// ---------------------------------------------------------------------------
// MFMA flash attention.  Block = (b*H+h, q-quarter): 64 queries, 4 waves x
// 16 q each.  512 blocks -> 2 blocks/CU co-residency.
// vp is TRANSPOSED [B,H,DK,N] -> Vt staged with vector loads/writes.
// ---------------------------------------------------------------------------
__global__ __launch_bounds__(256)
void attn_mfma_kernel(const u16* __restrict__ qp, const u16* __restrict__ kp,
                      const u16* __restrict__ vp, const _Float16* __restrict__ lb,
                      u16* __restrict__ ao)
{
    __shared__ __align__(16) u16 Ks[32][136];
    __shared__ __align__(16) u16 Vt[128][40];
    __shared__ __align__(16) u16 Ps[4][16][40];

    const int tid  = threadIdx.x;
    const int lane = tid & 63;
    const int w    = tid >> 6;
    const int l15  = lane & 15;
    const int l4   = lane >> 4;
    const int bh   = blockIdx.x >> 2;
    const int qt   = blockIdx.x & 3;
    const int q0   = qt * 64 + w * 16;

    s8v qf[4];
    const u16* qb = qp + ((size_t)bh * N_ + q0) * DK_;
#pragma unroll
    for (int ks = 0; ks < 4; ++ks)
        qf[ks] = *(const s8v*)(qb + (size_t)l15 * DK_ + ks * 32 + l4 * 8);

    f4v o[8] = {};
    float m_r[4], l_r[4];
#pragma unroll
    for (int r = 0; r < 4; ++r) { m_r[r] = -INFINITY; l_r[r] = 0.0f; }

    const float scale = 0.08838834764831845f;
    const _Float16* lbb = lb + ((size_t)bh * N_ + q0) * N_;

    const int sr = tid >> 3;
    const int sc = (tid & 7) * 16;
    const int vr = tid >> 2;
    const int vs = (tid & 3) * 8;

    for (int kt = 0; kt < 8; ++kt) {
        __syncthreads();
        {
            const u16* ksrc = kp + ((size_t)bh * N_ + kt * 32) * DK_;
            *(s8v*)&Ks[sr][sc]     = *(const s8v*)(ksrc + (size_t)sr * DK_ + sc);
            *(s8v*)&Ks[sr][sc + 8] = *(const s8v*)(ksrc + (size_t)sr * DK_ + sc + 8);
        }
        {
            const u16* vsrc = vp + ((size_t)bh * DK_ + vr) * N_ + kt * 32 + vs;
            const s8v v0 = *(const s8v*)vsrc;
            const s8v v1 = *(const s8v*)(vsrc + 64 * N_);
            *(s8v*)&Vt[vr][vs]      = v0;
            *(s8v*)&Vt[vr + 64][vs] = v1;
        }
        __syncthreads();

        f4v s[2] = {};
#pragma unroll
        for (int ks = 0; ks < 4; ++ks) {
#pragma unroll
            for (int kf = 0; kf < 2; ++kf) {
                const s8v kb = *(const s8v*)&Ks[kf * 16 + l15][ks * 32 + l4 * 8];
                s[kf] = __builtin_amdgcn_mfma_f32_16x16x32_bf16(
                    qf[ks], kb, s[kf], 0, 0, 0);
            }
        }
#pragma unroll
        for (int kf = 0; kf < 2; ++kf)
#pragma unroll
            for (int r = 0; r < 4; ++r)
                s[kf][r] = fmaf(s[kf][r], scale, (float)
                    lbb[(size_t)(l4 * 4 + r) * N_ + kt * 32 + kf * 16 + l15]);

        {
            float rm[4], al[4];
#pragma unroll
            for (int r = 0; r < 4; ++r) rm[r] = fmaxf(s[0][r], s[1][r]);
#pragma unroll
            for (int st = 1; st <= 8; st <<= 1)
#pragma unroll
                for (int r = 0; r < 4; ++r) rm[r] = fmaxf(rm[r], __shfl_xor(rm[r], st));
#pragma unroll
            for (int r = 0; r < 4; ++r) {
                const float mn = fmaxf(m_r[r], rm[r]);
                al[r] = __expf(m_r[r] - mn);
                m_r[r] = mn;
            }
            float p0[4], p1[4], rs[4];
#pragma unroll
            for (int r = 0; r < 4; ++r) {
                p0[r] = __expf(s[0][r] - m_r[r]);
                p1[r] = __expf(s[1][r] - m_r[r]);
                rs[r] = p0[r] + p1[r];
            }
#pragma unroll
            for (int st = 1; st <= 8; st <<= 1)
#pragma unroll
                for (int r = 0; r < 4; ++r) rs[r] += __shfl_xor(rs[r], st);
#pragma unroll
            for (int r = 0; r < 4; ++r) {
                l_r[r] = l_r[r] * al[r] + rs[r];
                Ps[w][l4 * 4 + r][l15]      = f2b(p0[r]);
                Ps[w][l4 * 4 + r][16 + l15] = f2b(p1[r]);
            }
#pragma unroll
            for (int nf = 0; nf < 8; ++nf)
#pragma unroll
                for (int r = 0; r < 4; ++r) o[nf][r] *= al[r];
        }

        const s8v pa = *(const s8v*)&Ps[w][l15][l4 * 8];
#pragma unroll
        for (int nf = 0; nf < 8; ++nf) {
            const s8v vb = *(const s8v*)&Vt[nf * 16 + l15][l4 * 8];
            o[nf] = __builtin_amdgcn_mfma_f32_16x16x32_bf16(pa, vb, o[nf], 0, 0, 0);
        }
    }

    const int b = bh >> 3, h = bh & 7;
    float inv[4];
#pragma unroll
    for (int r = 0; r < 4; ++r) inv[r] = 1.0f / l_r[r];
#pragma unroll
    for (int nf = 0; nf < 8; ++nf) {
#pragma unroll
        for (int r = 0; r < 4; ++r) {
            const int tok = q0 + l4 * 4 + r;
            const int d = nf * 16 + l15;
            ao[(((size_t)b * N_ + tok) * H_ + h) * DK_ + d] = f2b(o[nf][r] * inv[r]);
        }
    }
}

// ---------------------------------------------------------------------------
// Workspace (88 MiB used):
//   xb 24 MiB | Wt 8 MiB | qkv 24 MiB | lb(fp16) 16 MiB | ao 8 MiB
// ---------------------------------------------------------------------------
extern "C" void kernel_launch(void* const* d_in, const int* in_sizes, int n_in,
                              void* d_out, int out_size, void* d_ws, size_t ws_size,
                              hipStream_t stream)
{
    const float* xq = (const float*)d_in[0];
    const float* xk = (const float*)d_in[1];
    const float* xv = (const float*)d_in[2];
    const float* fg = (const float*)d_in[3];
    const float* Wq = (const float*)d_in[4];
    const float* bq = (const float*)d_in[5];
    const float* Wk = (const float*)d_in[6];
    const float* bk = (const float*)d_in[7];
    const float* Wv = (const float*)d_in[8];
    const float* bv = (const float*)d_in[9];
    const float* Wg = (const float*)d_in[10];
    const float* bg = (const float*)d_in[11];
    const float* Wo = (const float*)d_in[12];
    const float* bo = (const float*)d_in[13];

    char* w8 = (char*)d_ws;
    u16*      xb  = (u16*)(w8);
    u16*      Wt  = (u16*)(w8 + 25165824);
    u16*      qkv = (u16*)(w8 + 33554432);
    _Float16* lb  = (_Float16*)(w8 + 58720256);
    u16*      ao  = (u16*)(w8 + 75497472);

    cvt_kernel<<<dim3(2048, 3), 256, 0, stream>>>(xq, xk, xv, xb);
    cvtT_kernel<<<dim3(32, 32, 4), 256, 0, stream>>>(Wq, Wk, Wv, Wo, Wt);

    // batched qkv projection: 768 workgroups = 3 blocks/CU, 128x128 tile
    gemm_kernel<128, 4, 4, 1><<<dim3(256, 1, 3), 256, 0, stream>>>(
        xb, Wt, bq, bk, bv, qkv);

    boxbias_kernel<<<B_ * N_, 256, 0, stream>>>(fg, Wg, bg, lb);

    attn_mfma_kernel<<<512, 256, 0, stream>>>(
        qkv, qkv + 4194304, qkv + 2 * 4194304, lb, ao);

    // output projection: 128x128 tile, 256 workgroups (r12 A/B: amortize
    // the fixed K-step overhead with 16 MFMA/step instead of 8)
    gemm_kernel<128, 4, 4, 0><<<dim3(256, 1, 1), 256, 0, stream>>>(
        ao, Wt + 3 * 1048576, bo, bo, bo, d_out);
}

// Round 14
// 124.566 us; speedup vs baseline: 1.1950x; 1.0358x over previous
//
#include <hip/hip_runtime.h>
#include <hip/hip_bf16.h>
#include <hip/hip_fp16.h>
#include <math.h>

#define B_  16
#define N_  256
#define D_  1024
#define H_  8
#define DK_ 128

typedef unsigned short u16;
typedef __attribute__((ext_vector_type(8))) short s8v;   // 8 bf16 MFMA A/B frag
typedef __attribute__((ext_vector_type(4))) float f4v;   // MFMA C/D frag

__device__ __forceinline__ u16 f2b(float x) {
    union { float f; unsigned u; } v; v.f = x;
    unsigned r = v.u + 0x7fffu + ((v.u >> 16) & 1u);   // RNE
    return (u16)(r >> 16);
}

__device__ __forceinline__ void gload16(void* lds, const void* g) {
    __builtin_amdgcn_global_load_lds(
        (const __attribute__((address_space(1))) void*)g,
        (__attribute__((address_space(3))) void*)lds, 16, 0, 0);
}

// counted vmcnt waits (literal asm, memory clobber pins surrounding mem ops)
__device__ __forceinline__ void waitv8() { asm volatile("s_waitcnt vmcnt(8)" ::: "memory"); }
__device__ __forceinline__ void waitv6() { asm volatile("s_waitcnt vmcnt(6)" ::: "memory"); }
__device__ __forceinline__ void waitv4() { asm volatile("s_waitcnt vmcnt(4)" ::: "memory"); }
__device__ __forceinline__ void waitv3() { asm volatile("s_waitcnt vmcnt(3)" ::: "memory"); }
__device__ __forceinline__ void waitv0() { asm volatile("s_waitcnt vmcnt(0)" ::: "memory"); }
__device__ __forceinline__ void membar() { asm volatile("" ::: "memory"); }

// ---------------------------------------------------------------------------
// prep: fused fp32->bf16 convert (q/k/v) + weight convert/transpose.
// Both paths small-resource, BW-bound (r9 mixing hazard absent).
// Grid 10240 x 256: [0,6144) cvt | [6144,10240) cvtT.
// ---------------------------------------------------------------------------
__global__ __launch_bounds__(256)
void prep_kernel(const float* __restrict__ x0, const float* __restrict__ x1,
                 const float* __restrict__ x2,
                 const float* __restrict__ W0, const float* __restrict__ W1,
                 const float* __restrict__ W2, const float* __restrict__ W3,
                 u16* __restrict__ xb, u16* __restrict__ Wt)
{
    const int bx = blockIdx.x;
    const int tid = threadIdx.x;
    if (bx < 6144) {
        // ---- fp32 -> bf16 convert, 8 elems/thread ----
        const int y = bx >> 11;                 // 0..2 (q/k/v)
        const float* in = (y == 0) ? x0 : (y == 1) ? x1 : x2;
        u16* o = xb + (size_t)y * 4194304;
        const int i = (bx & 2047) * 256 + tid;
        const float4 a = ((const float4*)in)[2 * i];
        const float4 b = ((const float4*)in)[2 * i + 1];
        union { u16 s[8]; uint4 v; } t;
        t.s[0] = f2b(a.x); t.s[1] = f2b(a.y); t.s[2] = f2b(a.z); t.s[3] = f2b(a.w);
        t.s[4] = f2b(b.x); t.s[5] = f2b(b.y); t.s[6] = f2b(b.z); t.s[7] = f2b(b.w);
        ((uint4*)o)[i] = t.v;
    } else {
        // ---- weight convert + transpose: W[K][N] -> Wt[N][K] bf16 ----
        __shared__ float t[32][33];
        const int tt = bx - 6144;               // 0..4095
        const int z  = tt >> 10;
        const int rem = tt & 1023;
        const int k0 = (rem & 31) * 32;
        const int n0 = (rem >> 5) * 32;
        const float* W = (z == 0) ? W0 : (z == 1) ? W1 : (z == 2) ? W2 : W3;
        u16* o = Wt + (size_t)z * (D_ * D_);
        const int c = tid & 31, r8 = tid >> 5;
#pragma unroll
        for (int rr = 0; rr < 4; ++rr)
            t[r8 + rr * 8][c] = W[(size_t)(k0 + r8 + rr * 8) * D_ + n0 + c];
        __syncthreads();
#pragma unroll
        for (int rr = 0; rr < 4; ++rr)
            o[(size_t)(n0 + r8 + rr * 8) * D_ + k0 + c] = f2b(t[c][r8 + rr * 8]);
    }
}

// ---------------------------------------------------------------------------
// bf16 MFMA GEMM, 3-deep buffered K-pipeline with counted vmcnt (T4).
// out = A[4096,1024] @ Wt[1024,1024]^T + bias.  BN=128, BK=32, 256 thr =
// 4 waves (2 x 2), wave tile WM x 64, FM x 4 16x16 frags.
//   BM=128/FM=4/LOADS=4 : qkv projection (MODE 1, z batches slices)
//   BM= 64/FM=2/LOADS=3 : output proj (MODE 0, fp32 row-major) - 512 blocks
// Schedule per K-step: bar; STAGE(kt+2); vmcnt(2L) [tile kt landed]; bar;
// ds_read + MFMA.  Loads stay in flight across 2 compute phases (~HBM lat).
// Bank-conflict-free via XOR swizzle on (source col, read col) pair.
// ---------------------------------------------------------------------------
template<int BM, int FM, int LOADS, int MODE>
__global__ __launch_bounds__(256)
void gemm_kernel(const u16* __restrict__ A0, const u16* __restrict__ Wt0,
                 const float* __restrict__ b0, const float* __restrict__ b1,
                 const float* __restrict__ b2, void* __restrict__ outb)
{
    constexpr int WM  = FM * 16;
    constexpr int MT8 = (4096 / BM) / 8;   // m-tiles per XCD chunk
    __shared__ __align__(16) u16 As[3][BM][32];
    __shared__ __align__(16) u16 Bs[3][128][32];

    const int z = blockIdx.z;
    const u16* A  = A0  + (size_t)z * 4194304;
    const u16* Wt = Wt0 + (size_t)z * 1048576;
    const float* bias = (z == 0) ? b0 : (z == 1) ? b1 : b2;

    // bijective XCD-chunk swizzle
    const int bid = blockIdx.x;
    const int xcd = bid & 7;
    const int wic = bid >> 3;
    const int by  = xcd * MT8 + (wic & (MT8 - 1));
    const int bx  = wic / MT8;
    const int m0  = by * BM;
    const int n0  = bx * 128;

    const int tid  = threadIdx.x;
    const int lane = tid & 63;
    const int w    = tid >> 6;
    const int l15  = lane & 15;
    const int l4   = lane >> 4;
    const int wr   = w >> 1;
    const int wc   = w & 1;

    // staging: thread t -> row t>>2, 16B chunk c4; LDS dest linear,
    // global source col XOR-swizzled (involution with frag-read col)
    const int gr   = tid >> 2;
    const int c4   = tid & 3;
    const int scol = (c4 ^ ((gr >> 1) & 3)) * 8;
    const int doff = c4 * 8;
    const u16* asrc = A  + (size_t)(m0 + gr) * 1024 + scol;
    const u16* bsrc = Wt + (size_t)(n0 + gr) * 1024 + scol;
    const int fc = (l4 ^ ((l15 >> 1) & 3)) * 8;   // frag-read swizzled col

    auto stage = [&](int buf, int kt) {
        const int k0_ = kt * 32;
        gload16(&As[buf][gr][doff], asrc + k0_);
        if constexpr (BM == 128)
            gload16(&As[buf][gr + 64][doff], asrc + 64 * 1024 + k0_);
        gload16(&Bs[buf][gr][doff], bsrc + k0_);
        gload16(&Bs[buf][gr + 64][doff], bsrc + 64 * 1024 + k0_);
    };

    f4v acc[FM][4] = {};

    stage(0, 0);
    stage(1, 1);
    int cur = 0, stg = 2;

    for (int kt = 0; kt < 32; ++kt) {
        membar();
        __builtin_amdgcn_s_barrier();   // prior reads of buf[stg] done
        if (kt < 30) {
            stage(stg, kt + 2);
            if constexpr (LOADS == 4) waitv8(); else waitv6();
        } else if (kt == 30) {
            if constexpr (LOADS == 4) waitv4(); else waitv3();
        } else {
            waitv0();
        }
        membar();
        __builtin_amdgcn_s_barrier();   // tile kt fully in LDS for all waves

        s8v af[FM], bf[4];
#pragma unroll
        for (int i = 0; i < FM; ++i)
            af[i] = *(const s8v*)&As[cur][wr * WM + i * 16 + l15][fc];
#pragma unroll
        for (int j = 0; j < 4; ++j)
            bf[j] = *(const s8v*)&Bs[cur][wc * 64 + j * 16 + l15][fc];
#pragma unroll
        for (int i = 0; i < FM; ++i)
#pragma unroll
            for (int j = 0; j < 4; ++j)
                acc[i][j] = __builtin_amdgcn_mfma_f32_16x16x32_bf16(
                    af[i], bf[j], acc[i][j], 0, 0, 0);

        cur = (cur == 2) ? 0 : cur + 1;
        stg = (stg == 2) ? 0 : stg + 1;
    }

    // epilogue: C/D layout col = lane&15, row = (lane>>4)*4 + reg
#pragma unroll
    for (int j = 0; j < 4; ++j) {
        const int n = n0 + wc * 64 + j * 16 + l15;
        const float bb = bias[n];
#pragma unroll
        for (int i = 0; i < FM; ++i) {
            const int mbase = m0 + wr * WM + i * 16 + l4 * 4;
            if constexpr (MODE == 0) {
#pragma unroll
                for (int reg = 0; reg < 4; ++reg)
                    ((float*)outb)[(size_t)(mbase + reg) * 1024 + n] =
                        acc[i][j][reg] + bb;
            } else {
                if (z == 2) {
                    // transposed V: [B,H,DK,N], 4 consecutive tok -> ushort4
                    const int b = mbase >> 8, tok = mbase & 255;
                    const int h = n >> 7, d = n & 127;
                    ushort4 st;
                    st.x = f2b(acc[i][j][0] + bb);
                    st.y = f2b(acc[i][j][1] + bb);
                    st.z = f2b(acc[i][j][2] + bb);
                    st.w = f2b(acc[i][j][3] + bb);
                    *(ushort4*)&((u16*)outb)[(size_t)z * 4194304 +
                        (((size_t)b * H_ + h) * DK_ + d) * N_ + tok] = st;
                } else {
                    const int h = n >> 7, d = n & 127;
#pragma unroll
                    for (int reg = 0; reg < 4; ++reg) {
                        const int m = mbase + reg;
                        const int b = m >> 8, tok = m & 255;
                        ((u16*)outb)[(size_t)z * 4194304 +
                            (((size_t)b * H_ + h) * N_ + tok) * DK_ + d] =
                            f2b(acc[i][j][reg] + bb);
                    }
                }
            }
        }
    }
}

// ---------------------------------------------------------------------------
// Fused box relational embedding -> per-head Linear(64->1) -> relu -> log.
// Output fp16 [B,H,N,N].  NO LDS: Wg/bg read at wave-uniform addresses ->
// compiler emits s_load + SGPR-operand v_fmac (zero vector-mem in the dot).
// ---------------------------------------------------------------------------
__global__ __launch_bounds__(256)
void boxbias_kernel(const float* __restrict__ fg, const float* __restrict__ Wg,
                    const float* __restrict__ bg, _Float16* __restrict__ lb)
{
    const int tid = threadIdx.x;
    const int b = blockIdx.x >> 8;
    const int i = blockIdx.x & 255;

    const float4 bi = *(const float4*)&fg[(size_t)(b * N_ + i) * 4];
    const float cxi = 0.5f * (bi.x + bi.z);
    const float cyi = 0.5f * (bi.y + bi.w);
    const float wi  = bi.z - bi.x + 1.0f;
    const float hi  = bi.w - bi.y + 1.0f;

    const int j = tid;
    const float4 bj = *(const float4*)&fg[(size_t)(b * N_ + j) * 4];
    const float cxj = 0.5f * (bj.x + bj.z);
    const float cyj = 0.5f * (bj.y + bj.w);
    const float wj  = bj.z - bj.x + 1.0f;
    const float hj  = bj.w - bj.y + 1.0f;

    const float pos[4] = {
        logf(fmaxf(fabsf((cxi - cxj) / wi), 1e-3f)) * 100.0f,
        logf(fmaxf(fabsf((cyi - cyj) / hi), 1e-3f)) * 100.0f,
        logf(wi / wj) * 100.0f,
        logf(hi / hj) * 100.0f
    };
    const float dim[8] = {1.0f, 0.421696503f, 0.177827941f, 0.0749894209f,
                          0.0316227766f, 0.0133352143f, 0.00562341325f, 0.00237137371f};

    float sv[32], cv[32];
#pragma unroll
    for (int p = 0; p < 4; ++p)
#pragma unroll
        for (int q = 0; q < 8; ++q)
            __sincosf(pos[p] * dim[q], &sv[p * 8 + q], &cv[p * 8 + q]);

#pragma unroll
    for (int h = 0; h < 8; ++h) {
        float acc = bg[h];
        const float* wrow = Wg + h * 64;      // wave-uniform -> s_load
#pragma unroll
        for (int g = 0; g < 32; ++g)
            acc = fmaf(sv[g], wrow[g], fmaf(cv[g], wrow[32 + g], acc));
        const float rel = fmaxf(acc, 0.0f);
        lb[(((size_t)b * H_ + h) * N_ + i) * N_ + j] =
            (_Float16)logf(fmaxf(rel, 1e-6f));
    }
}

// ---------------------------------------------------------------------------
// MFMA flash attention.  Block = (b*H+h, q-quarter): 64 queries, 4 waves x
// 16 q each.  512 blocks -> 2 blocks/CU co-residency.
// vp is TRANSPOSED [B,H,DK,N] -> Vt staged with vector loads/writes.
// ---------------------------------------------------------------------------
__global__ __launch_bounds__(256)
void attn_mfma_kernel(const u16* __restrict__ qp, const u16* __restrict__ kp,
                      const u16* __restrict__ vp, const _Float16* __restrict__ lb,
                      u16* __restrict__ ao)
{
    __shared__ __align__(16) u16 Ks[32][136];
    __shared__ __align__(16) u16 Vt[128][40];
    __shared__ __align__(16) u16 Ps[4][16][40];

    const int tid  = threadIdx.x;
    const int lane = tid & 63;
    const int w    = tid >> 6;
    const int l15  = lane & 15;
    const int l4   = lane >> 4;
    const int bh   = blockIdx.x >> 2;
    const int qt   = blockIdx.x & 3;
    const int q0   = qt * 64 + w * 16;

    s8v qf[4];
    const u16* qb = qp + ((size_t)bh * N_ + q0) * DK_;
#pragma unroll
    for (int ks = 0; ks < 4; ++ks)
        qf[ks] = *(const s8v*)(qb + (size_t)l15 * DK_ + ks * 32 + l4 * 8);

    f4v o[8] = {};
    float m_r[4], l_r[4];
#pragma unroll
    for (int r = 0; r < 4; ++r) { m_r[r] = -INFINITY; l_r[r] = 0.0f; }

    const float scale = 0.08838834764831845f;
    const _Float16* lbb = lb + ((size_t)bh * N_ + q0) * N_;

    const int sr = tid >> 3;
    const int sc = (tid & 7) * 16;
    const int vr = tid >> 2;
    const int vs = (tid & 3) * 8;

    for (int kt = 0; kt < 8; ++kt) {
        __syncthreads();
        {
            const u16* ksrc = kp + ((size_t)bh * N_ + kt * 32) * DK_;
            *(s8v*)&Ks[sr][sc]     = *(const s8v*)(ksrc + (size_t)sr * DK_ + sc);
            *(s8v*)&Ks[sr][sc + 8] = *(const s8v*)(ksrc + (size_t)sr * DK_ + sc + 8);
        }
        {
            const u16* vsrc = vp + ((size_t)bh * DK_ + vr) * N_ + kt * 32 + vs;
            const s8v v0 = *(const s8v*)vsrc;
            const s8v v1 = *(const s8v*)(vsrc + 64 * N_);
            *(s8v*)&Vt[vr][vs]      = v0;
            *(s8v*)&Vt[vr + 64][vs] = v1;
        }
        __syncthreads();

        f4v s[2] = {};
#pragma unroll
        for (int ks = 0; ks < 4; ++ks) {
#pragma unroll
            for (int kf = 0; kf < 2; ++kf) {
                const s8v kb = *(const s8v*)&Ks[kf * 16 + l15][ks * 32 + l4 * 8];
                s[kf] = __builtin_amdgcn_mfma_f32_16x16x32_bf16(
                    qf[ks], kb, s[kf], 0, 0, 0);
            }
        }
#pragma unroll
        for (int kf = 0; kf < 2; ++kf)
#pragma unroll
            for (int r = 0; r < 4; ++r)
                s[kf][r] = fmaf(s[kf][r], scale, (float)
                    lbb[(size_t)(l4 * 4 + r) * N_ + kt * 32 + kf * 16 + l15]);

        {
            float rm[4], al[4];
#pragma unroll
            for (int r = 0; r < 4; ++r) rm[r] = fmaxf(s[0][r], s[1][r]);
#pragma unroll
            for (int st = 1; st <= 8; st <<= 1)
#pragma unroll
                for (int r = 0; r < 4; ++r) rm[r] = fmaxf(rm[r], __shfl_xor(rm[r], st));
#pragma unroll
            for (int r = 0; r < 4; ++r) {
                const float mn = fmaxf(m_r[r], rm[r]);
                al[r] = __expf(m_r[r] - mn);
                m_r[r] = mn;
            }
            float p0[4], p1[4], rs[4];
#pragma unroll
            for (int r = 0; r < 4; ++r) {
                p0[r] = __expf(s[0][r] - m_r[r]);
                p1[r] = __expf(s[1][r] - m_r[r]);
                rs[r] = p0[r] + p1[r];
            }
#pragma unroll
            for (int st = 1; st <= 8; st <<= 1)
#pragma unroll
                for (int r = 0; r < 4; ++r) rs[r] += __shfl_xor(rs[r], st);
#pragma unroll
            for (int r = 0; r < 4; ++r) {
                l_r[r] = l_r[r] * al[r] + rs[r];
                Ps[w][l4 * 4 + r][l15]      = f2b(p0[r]);
                Ps[w][l4 * 4 + r][16 + l15] = f2b(p1[r]);
            }
#pragma unroll
            for (int nf = 0; nf < 8; ++nf)
#pragma unroll
                for (int r = 0; r < 4; ++r) o[nf][r] *= al[r];
        }

        const s8v pa = *(const s8v*)&Ps[w][l15][l4 * 8];
#pragma unroll
        for (int nf = 0; nf < 8; ++nf) {
            const s8v vb = *(const s8v*)&Vt[nf * 16 + l15][l4 * 8];
            o[nf] = __builtin_amdgcn_mfma_f32_16x16x32_bf16(pa, vb, o[nf], 0, 0, 0);
        }
    }

    const int b = bh >> 3, h = bh & 7;
    float inv[4];
#pragma unroll
    for (int r = 0; r < 4; ++r) inv[r] = 1.0f / l_r[r];
#pragma unroll
    for (int nf = 0; nf < 8; ++nf) {
#pragma unroll
        for (int r = 0; r < 4; ++r) {
            const int tok = q0 + l4 * 4 + r;
            const int d = nf * 16 + l15;
            ao[(((size_t)b * N_ + tok) * H_ + h) * DK_ + d] = f2b(o[nf][r] * inv[r]);
        }
    }
}

// ---------------------------------------------------------------------------
// Workspace (88 MiB used):
//   xb 24 MiB | Wt 8 MiB | qkv 24 MiB | lb(fp16) 16 MiB | ao 8 MiB
// ---------------------------------------------------------------------------
extern "C" void kernel_launch(void* const* d_in, const int* in_sizes, int n_in,
                              void* d_out, int out_size, void* d_ws, size_t ws_size,
                              hipStream_t stream)
{
    const float* xq = (const float*)d_in[0];
    const float* xk = (const float*)d_in[1];
    const float* xv = (const float*)d_in[2];
    const float* fg = (const float*)d_in[3];
    const float* Wq = (const float*)d_in[4];
    const float* bq = (const float*)d_in[5];
    const float* Wk = (const float*)d_in[6];
    const float* bk = (const float*)d_in[7];
    const float* Wv = (const float*)d_in[8];
    const float* bv = (const float*)d_in[9];
    const float* Wg = (const float*)d_in[10];
    const float* bg = (const float*)d_in[11];
    const float* Wo = (const float*)d_in[12];
    const float* bo = (const float*)d_in[13];

    char* w8 = (char*)d_ws;
    u16*      xb  = (u16*)(w8);
    u16*      Wt  = (u16*)(w8 + 25165824);
    u16*      qkv = (u16*)(w8 + 33554432);
    _Float16* lb  = (_Float16*)(w8 + 58720256);
    u16*      ao  = (u16*)(w8 + 75497472);

    // 1. conversions (merged cvt + cvtT; both BW-bound, small-resource)
    prep_kernel<<<10240, 256, 0, stream>>>(xq, xk, xv, Wq, Wk, Wv, Wo, xb, Wt);

    // 2. qkv projection: 768 workgroups = 3 blocks/CU, 128x128 tile
    gemm_kernel<128, 4, 4, 1><<<dim3(256, 1, 3), 256, 0, stream>>>(
        xb, Wt, bq, bk, bv, qkv);

    // 3. boxbias (no-LDS SGPR-dot form)
    boxbias_kernel<<<B_ * N_, 256, 0, stream>>>(fg, Wg, bg, lb);

    // 4. attention (512 blocks, 2/CU)
    attn_mfma_kernel<<<512, 256, 0, stream>>>(
        qkv, qkv + 4194304, qkv + 2 * 4194304, lb, ao);

    // 5. output projection: 512 workgroups = 2 blocks/CU, 64x128 tile
    gemm_kernel<64, 2, 3, 0><<<dim3(512, 1, 1), 256, 0, stream>>>(
        ao, Wt + 3 * 1048576, bo, bo, bo, d_out);
}